// Round 15
// baseline (190.808 us; speedup 1.0000x reference)
//
#include <hip/hip_runtime.h>
#include <math.h>

// AFM fused single-pass, row-run schedule, butterfly-free: one block = one
// sample, 512 threads (8 waves). Wave owns row r.
// Per row: A' = W^T * er folded ONCE (4 pk_mul) -> ds_read of ec feeds MFMA1
// DIRECTLY. Per 16-col tile:
//   MFMA1 (S = A' @ ec, C = bias) -> relu/pack -> MFMA2 (L = H_bcast @ relu(S),
//   16x16x16) -> every lane holds its col's logit in acc[0] -> w = exp2 ->
//   accu += w * ec (packed f16). Row epilogue: pool += er * accu.
// NO unions in the main loop (R13/R14 lesson: loop-carried unions defeat SROA
// -> alloca -> 0.5 GB scratch traffic). All state is plain SSA vectors;
// operand puns via __builtin_bit_cast, slices via __builtin_shufflevector.
// lsum rides the staging buffer's 9th slot. No shuffles in the main loop.
constexpr int kT = 100;
constexpr int kD = 32;
constexpr int kA = 16;
constexpr int kESH = 40;     // e row stride in halfs (80 B)
constexpr int kNT = 512;     // 8 waves

typedef float    float4v __attribute__((ext_vector_type(4)));
typedef __fp16   fp16x2  __attribute__((ext_vector_type(2)));
typedef __fp16   half4   __attribute__((ext_vector_type(4)));
typedef __fp16   half8   __attribute__((ext_vector_type(8)));
typedef _Float16 half4v  __attribute__((ext_vector_type(4)));
typedef _Float16 half8v  __attribute__((ext_vector_type(8)));

#if __has_builtin(__builtin_amdgcn_exp2f)
#define EXP2F(x) __builtin_amdgcn_exp2f(x)
#else
#define EXP2F(x) exp2f(x)
#endif

// LDS: she = 116 rows * 80 B = 9280 B (rows 100..115 zeroed: tail tiles read
// up to row 114); stg (512*9 floats = 18432 B) aliases after the main loop.
__global__ __launch_bounds__(kNT, 8)
void afm_kernel(const int* __restrict__ x,
                const float* __restrict__ Emb,
                const float* __restrict__ W,    // (32,16)
                const float* __restrict__ bb,   // (16,)
                const float* __restrict__ h,    // (16,)
                const float* __restrict__ W1,   // (32,16)
                const float* __restrict__ b1,   // (16,)
                const float* __restrict__ W2,   // (16,8)
                const float* __restrict__ b2,   // (8,)
                const float* __restrict__ Wf,   // (8,)
                const float* __restrict__ bf,   // (1,)
                float* __restrict__ out)        // (1024,)
{
    __shared__ __align__(16) unsigned char smem[18432];
    __shared__ float sh_pooled[kD];
    __shared__ float sh_o1[kA];
    __shared__ float sh_o2[8];

    __fp16* she = (__fp16*)smem;
    const char* sheb = (const char*)smem;

    const int tid  = threadIdx.x;
    const int b    = blockIdx.x;
    const int lane = tid & 63;
    const int wv   = tid >> 6;           // 0..7
    const int quad = lane >> 4;
    const int l15  = lane & 15;
    const int k0   = quad * 8;           // MFMA1 K slice (dims k0..k0+7)

    // ---- gather embeddings -> f16 LDS; zero rows 100..115 ----
    const int* xb = x + b * kT;
    for (int i = tid; i < kT * 8; i += kNT) {
        const int row = i >> 3, c4 = i & 7;
        const int v = xb[row];
        const float4 val = ((const float4*)Emb)[v * 8 + c4];
        const fp16x2 lo = __builtin_amdgcn_cvt_pkrtz(val.x, val.y);
        const fp16x2 hi = __builtin_amdgcn_cvt_pkrtz(val.z, val.w);
        const half4 h4 = {lo[0], lo[1], hi[0], hi[1]};
        *(half4*)(she + row * kESH + c4 * 4) = h4;
    }
    if (tid < 16 * kESH / 2)             // 320 u32 of zero pad (rows 100..115)
        ((unsigned int*)she)[kT * kESH / 2 + tid] = 0u;

    // ---- W^T f16 A-template (lane holds W[k0+j][a=l15]); bias as C ----
    half8 wa;
#pragma unroll
    for (int j = 0; j < 4; ++j) {
        const fp16x2 p = __builtin_amdgcn_cvt_pkrtz(W[(k0 + 2 * j) * kA + l15],
                                                    W[(k0 + 2 * j + 1) * kA + l15]);
        wa[2 * j] = p[0];
        wa[2 * j + 1] = p[1];
    }
    float4v bfrag;
#pragma unroll
    for (int rg = 0; rg < 4; ++rg) bfrag[rg] = bb[quad * 4 + rg];

    // ---- MFMA2 A-frag: H broadcast; lane holds A[m=l15][k=quad*4+i]=h[k]*log2e
    const fp16x2 hf01 = __builtin_amdgcn_cvt_pkrtz(h[quad * 4 + 0] * 1.44269504f,
                                                   h[quad * 4 + 1] * 1.44269504f);
    const fp16x2 hf23 = __builtin_amdgcn_cvt_pkrtz(h[quad * 4 + 2] * 1.44269504f,
                                                   h[quad * 4 + 3] * 1.44269504f);
    const half4 hfv = {hf01[0], hf01[1], hf23[0], hf23[1]};
    const half4v hf_mf = __builtin_bit_cast(half4v, hfv);
    const float4v zero4 = {0.0f, 0.0f, 0.0f, 0.0f};

    const int lane_base = l15 * 80 + quad * 16;   // byte offset for ec
    __syncthreads();

    // ---- fused main loop over rows ----
    fp16x2 pool2[4];
    const fp16x2 zz = {(__fp16)0.0f, (__fp16)0.0f};
#pragma unroll
    for (int j = 0; j < 4; ++j) pool2[j] = zz;
    float lsum = 0.0f;

    auto do_row = [&](int r) {
        const int len = 99 - r;                        // pairs in this row (>=1)
        const int ntiles = (len + 15) >> 4;
        const int rem = len - ((ntiles - 1) << 4);     // tail cols (1..16)
        const half8 er = *(const half8*)(sheb + r * 80 + quad * 16);  // broadcast
        const half8 ap = wa * er;                      // fold er into A (4 pk_mul/ROW)
        const half8v ap_mf = __builtin_bit_cast(half8v, ap);
        int coff = (r + 1) * 80 + lane_base;
        fp16x2 accu[4];
#pragma unroll
        for (int j = 0; j < 4; ++j) accu[j] = zz;
        for (int t = 0; t < ntiles; ++t, coff += 1280) {
            const half8 ec = *(const half8*)(sheb + coff);   // feeds MFMA1 directly
            float4v s1 = __builtin_amdgcn_mfma_f32_16x16x32_f16(
                ap_mf, __builtin_bit_cast(half8v, ec), bfrag, 0, 0, 0);
            const fp16x2 r01 = __builtin_amdgcn_cvt_pkrtz(fmaxf(s1[0], 0.0f),
                                                          fmaxf(s1[1], 0.0f));
            const fp16x2 r23 = __builtin_amdgcn_cvt_pkrtz(fmaxf(s1[2], 0.0f),
                                                          fmaxf(s1[3], 0.0f));
            const half4 rlv = {r01[0], r01[1], r23[0], r23[1]};
            float4v l4 = __builtin_amdgcn_mfma_f32_16x16x16f16(
                hf_mf, __builtin_bit_cast(half4v, rlv), zero4, 0, 0, 0);
            float w = EXP2F(l4[0]);
            if (t == ntiles - 1) w = (l15 < rem) ? w : 0.0f;
            lsum += w;
            const fp16x2 ww = __builtin_amdgcn_cvt_pkrtz(w, w);
#pragma unroll
            for (int j = 0; j < 4; ++j) {
                const fp16x2 ecj = __builtin_shufflevector(ec, ec, 0, 1) * zz; // placeholder avoided
            }
            // accu += w * ec  (packed f16; slices are plain shuffles)
            accu[0] += ww * __builtin_shufflevector(ec, ec, 0, 1);
            accu[1] += ww * __builtin_shufflevector(ec, ec, 2, 3);
            accu[2] += ww * __builtin_shufflevector(ec, ec, 4, 5);
            accu[3] += ww * __builtin_shufflevector(ec, ec, 6, 7);
        }
        // row epilogue: pool += er * accu
        pool2[0] += __builtin_shufflevector(er, er, 0, 1) * accu[0];
        pool2[1] += __builtin_shufflevector(er, er, 2, 3) * accu[1];
        pool2[2] += __builtin_shufflevector(er, er, 4, 5) * accu[2];
        pool2[3] += __builtin_shufflevector(er, er, 6, 7) * accu[3];
    };

    // rows paired (g*16+wvg, g*16+15-wvg); rotate wvg per g to balance
    for (int g = 0; g < 6; ++g) {
        const int wvg = (wv + g) & 7;
        do_row(g * 16 + wvg);
        do_row(g * 16 + 15 - wvg);
    }
    if (wv < 3) do_row(96 + wv);                       // rows 96..98

    __syncthreads();                 // she reads done; smem reusable
    float* stg = (float*)smem;       // 512 * 9 floats = 18432 B
#pragma unroll
    for (int j = 0; j < 4; ++j) {
        stg[tid * 9 + 2 * j]     = (float)pool2[j][0];
        stg[tid * 9 + 2 * j + 1] = (float)pool2[j][1];
    }
    stg[tid * 9 + 8] = lsum;         // per-thread w-sum rides slot 8
    __syncthreads();

    // pooled[d]: lanes with quad == d>>3 carry pool[j]; their lsum sums to total
    if (tid < kD) {
        const int q = tid >> 3, j = tid & 7;
        float s = 0.0f, sw = 0.0f;
        for (int w8 = 0; w8 < 8; ++w8)
            for (int l = 0; l < 16; ++l) {
                const float* row = stg + (w8 * 64 + q * 16 + l) * 9;
                s += row[j];
                sw += row[8];
            }
        sh_pooled[tid] = s / sw;
    }
    __syncthreads();

    // ---- MLP head ----
    if (tid < kA) {
        float o = b1[tid];
#pragma unroll
        for (int d = 0; d < kD; ++d) o = fmaf(sh_pooled[d], W1[d * kA + tid], o);
        sh_o1[tid] = fmaxf(o, 0.0f);
    }
    __syncthreads();
    if (tid < 8) {
        float o = b2[tid];
#pragma unroll
        for (int a = 0; a < kA; ++a) o = fmaf(sh_o1[a], W2[a * 8 + tid], o);
        sh_o2[tid] = fmaxf(o, 0.0f);
    }
    __syncthreads();
    if (tid == 0) {
        float z = bf[0];
#pragma unroll
        for (int j = 0; j < 8; ++j) z = fmaf(sh_o2[j], Wf[j], z);
        out[b] = 1.0f / (1.0f + __expf(-z));
    }
}

extern "C" void kernel_launch(void* const* d_in, const int* in_sizes, int n_in,
                              void* d_out, int out_size, void* d_ws, size_t ws_size,
                              hipStream_t stream) {
    const int*   x   = (const int*)d_in[0];
    const float* Emb = (const float*)d_in[1];
    const float* W   = (const float*)d_in[2];
    const float* bb  = (const float*)d_in[3];
    const float* h   = (const float*)d_in[4];
    const float* W1  = (const float*)d_in[5];
    const float* b1  = (const float*)d_in[6];
    const float* W2  = (const float*)d_in[7];
    const float* b2  = (const float*)d_in[8];
    const float* Wf  = (const float*)d_in[9];
    const float* bf  = (const float*)d_in[10];
    float* out = (float*)d_out;

    afm_kernel<<<1024, kNT, 0, stream>>>(x, Emb, W, bb, h, W1, b1, W2, b2, Wf, bf, out);
}

// Round 16
// 107.086 us; speedup vs baseline: 1.7818x; 1.7818x over previous
//
#include <hip/hip_runtime.h>
#include <math.h>

// AFM fused single-pass, row-run schedule, butterfly-free: one block = one
// sample, 512 threads (8 waves). Wave owns row r; er loaded once/row.
// Per 16-col tile:
//   MFMA1: S^T(16a x 16p) = W^T @ HB^T  (mfma_f32_16x16x32_f16, C = bias)
//   relu+pack -> B-frag;  MFMA2: L = H_bcast @ relu(S^T)  (mfma_f32_16x16x16f16)
//   -> EVERY lane holds logit_p for its col p in acc2[0]; no shuffles at all.
// w = exp2(logit*log2e) (no-max softmax: |logit| < ~0.5), pool in packed f16.
// lsum rides the staging buffer's 9th slot.
// R16 delta vs R12: do_row dispatches on nfull via switch -> each case is
// STRAIGHT-LINE code with k independent tile bodies, letting the compiler
// hoist all k ds_read_b128s (hides the ~120-cyc LDS latency, the longest
// link of the per-tile dep chain). No loop-carried state (R13-R15 lesson:
// that path ends in alloca/scratch, 0.25-0.5 GB HBM churn).
constexpr int kT = 100;
constexpr int kD = 32;
constexpr int kA = 16;
constexpr int kESH = 40;     // e row stride in halfs (80 B)
constexpr int kNT = 512;     // 8 waves

typedef float    float4v __attribute__((ext_vector_type(4)));
typedef __fp16   fp16x2  __attribute__((ext_vector_type(2)));
typedef __fp16   half4   __attribute__((ext_vector_type(4)));
typedef __fp16   half8   __attribute__((ext_vector_type(8)));
typedef _Float16 half4v  __attribute__((ext_vector_type(4)));
typedef _Float16 half8v  __attribute__((ext_vector_type(8)));

#if __has_builtin(__builtin_amdgcn_exp2f)
#define EXP2F(x) __builtin_amdgcn_exp2f(x)
#else
#define EXP2F(x) exp2f(x)
#endif

// LDS: she = 116 rows * 80 B = 9280 B (rows 100..115 zeroed: tail tiles read
// up to row 114); stg (512*9 floats = 18432 B) aliases after the main loop.
__global__ __launch_bounds__(kNT, 8)
void afm_kernel(const int* __restrict__ x,
                const float* __restrict__ Emb,
                const float* __restrict__ W,    // (32,16)
                const float* __restrict__ bb,   // (16,)
                const float* __restrict__ h,    // (16,)
                const float* __restrict__ W1,   // (32,16)
                const float* __restrict__ b1,   // (16,)
                const float* __restrict__ W2,   // (16,8)
                const float* __restrict__ b2,   // (8,)
                const float* __restrict__ Wf,   // (8,)
                const float* __restrict__ bf,   // (1,)
                float* __restrict__ out)        // (1024,)
{
    __shared__ __align__(16) unsigned char smem[18432];
    __shared__ float sh_pooled[kD];
    __shared__ float sh_o1[kA];
    __shared__ float sh_o2[8];

    __fp16* she = (__fp16*)smem;
    const char* sheb = (const char*)smem;

    const int tid  = threadIdx.x;
    const int b    = blockIdx.x;
    const int lane = tid & 63;
    const int wv   = tid >> 6;           // 0..7
    const int quad = lane >> 4;
    const int l15  = lane & 15;
    const int k0   = quad * 8;           // MFMA1 K slice (dims k0..k0+7)

    // ---- gather embeddings -> f16 LDS; zero rows 100..115 ----
    const int* xb = x + b * kT;
    for (int i = tid; i < kT * 8; i += kNT) {
        const int row = i >> 3, c4 = i & 7;
        const int v = xb[row];
        const float4 val = ((const float4*)Emb)[v * 8 + c4];
        union { fp16x2 h2[2]; half4 h4; } tmp;
        tmp.h2[0] = __builtin_amdgcn_cvt_pkrtz(val.x, val.y);
        tmp.h2[1] = __builtin_amdgcn_cvt_pkrtz(val.z, val.w);
        *(half4*)(she + row * kESH + c4 * 4) = tmp.h4;
    }
    if (tid < 16 * kESH / 2)             // 320 u32 of zero pad (rows 100..115)
        ((unsigned int*)she)[kT * kESH / 2 + tid] = 0u;

    // ---- A-frag MFMA1: W^T f16 (lane holds W[k0+j][a=l15]); bias as C ----
    union { fp16x2 h2[4]; half8v h8; } wa;
#pragma unroll
    for (int j = 0; j < 4; ++j)
        wa.h2[j] = __builtin_amdgcn_cvt_pkrtz(W[(k0 + 2 * j) * kA + l15],
                                              W[(k0 + 2 * j + 1) * kA + l15]);
    float4v bfrag;
#pragma unroll
    for (int rg = 0; rg < 4; ++rg) bfrag[rg] = bb[quad * 4 + rg];

    // ---- A-frag MFMA2: H broadcast; lane holds A[m=l15][k=quad*4+i] = h[k]*log2e
    union { fp16x2 h2[2]; half4v v; } hf;
    hf.h2[0] = __builtin_amdgcn_cvt_pkrtz(h[quad * 4 + 0] * 1.44269504f,
                                          h[quad * 4 + 1] * 1.44269504f);
    hf.h2[1] = __builtin_amdgcn_cvt_pkrtz(h[quad * 4 + 2] * 1.44269504f,
                                          h[quad * 4 + 3] * 1.44269504f);
    const float4v zero4 = {0.0f, 0.0f, 0.0f, 0.0f};

    const int lane_base = l15 * 80 + quad * 16;   // byte offset for ec
    __syncthreads();

    // ---- fused main loop over rows ----
    fp16x2 pool2[4];
    const fp16x2 zz = {(__fp16)0.0f, (__fp16)0.0f};
#pragma unroll
    for (int j = 0; j < 4; ++j) pool2[j] = zz;
    float lsum = 0.0f;

    union HB { half8 fp; fp16x2 h2[4]; half8v mf; };

    auto do_tile = [&](const half8& er, int coff, int rem, bool mask) {
        HB hb;
        hb.fp = er * (*(const half8*)(sheb + coff));   // 4x v_pk_mul_f16
        float4v s1 = __builtin_amdgcn_mfma_f32_16x16x32_f16(wa.h8, hb.mf, bfrag, 0, 0, 0);
        // relu + pack as B-frag of MFMA2: B[k=quad*4+rg][n=l15]
        union { fp16x2 h2[2]; half4v v; } rl;
        rl.h2[0] = __builtin_amdgcn_cvt_pkrtz(fmaxf(s1[0], 0.0f), fmaxf(s1[1], 0.0f));
        rl.h2[1] = __builtin_amdgcn_cvt_pkrtz(fmaxf(s1[2], 0.0f), fmaxf(s1[3], 0.0f));
        // L = H_bcast @ relu(S^T): every lane's acc2[0] = logit_p * log2e
        float4v l4 = __builtin_amdgcn_mfma_f32_16x16x16f16(hf.v, rl.v, zero4, 0, 0, 0);
        float w = EXP2F(l4[0]);
        if (mask) w = (l15 < rem) ? w : 0.0f;
        lsum += w;
        const fp16x2 ww = __builtin_amdgcn_cvt_pkrtz(w, w);
#pragma unroll
        for (int j = 0; j < 4; ++j)
            pool2[j] += ww * hb.h2[j];                 // v_pk_fma_f16
    };

    auto do_row = [&](int r) {
        const int len = 99 - r;                        // pairs in this row (>=1)
        const int nfull = (len - 1) >> 4;              // full 16-col tiles (0..6)
        const int rem = len - (nfull << 4);            // tail cols (1..16)
        const half8 er = *(const half8*)(sheb + r * 80 + quad * 16);  // broadcast
        const int c0 = (r + 1) * 80 + lane_base;
        // straight-line full tiles: compiler hoists the ds_reads of a case
        switch (nfull) {
        case 6:
            do_tile(er, c0 + 0 * 1280, 16, false); do_tile(er, c0 + 1 * 1280, 16, false);
            do_tile(er, c0 + 2 * 1280, 16, false); do_tile(er, c0 + 3 * 1280, 16, false);
            do_tile(er, c0 + 4 * 1280, 16, false); do_tile(er, c0 + 5 * 1280, 16, false);
            break;
        case 5:
            do_tile(er, c0 + 0 * 1280, 16, false); do_tile(er, c0 + 1 * 1280, 16, false);
            do_tile(er, c0 + 2 * 1280, 16, false); do_tile(er, c0 + 3 * 1280, 16, false);
            do_tile(er, c0 + 4 * 1280, 16, false);
            break;
        case 4:
            do_tile(er, c0 + 0 * 1280, 16, false); do_tile(er, c0 + 1 * 1280, 16, false);
            do_tile(er, c0 + 2 * 1280, 16, false); do_tile(er, c0 + 3 * 1280, 16, false);
            break;
        case 3:
            do_tile(er, c0 + 0 * 1280, 16, false); do_tile(er, c0 + 1 * 1280, 16, false);
            do_tile(er, c0 + 2 * 1280, 16, false);
            break;
        case 2:
            do_tile(er, c0 + 0 * 1280, 16, false); do_tile(er, c0 + 1 * 1280, 16, false);
            break;
        case 1:
            do_tile(er, c0 + 0 * 1280, 16, false);
            break;
        default:
            break;
        }
        do_tile(er, c0 + nfull * 1280, rem, true);     // tail tile (rem in 1..16)
    };

    // rows paired (g*16+wvg, g*16+15-wvg); rotate wvg per g to balance
    for (int g = 0; g < 6; ++g) {
        const int wvg = (wv + g) & 7;
        do_row(g * 16 + wvg);
        do_row(g * 16 + 15 - wvg);
    }
    if (wv < 3) do_row(96 + wv);                       // rows 96..98

    __syncthreads();                 // she reads done; smem reusable
    float* stg = (float*)smem;       // 512 * 9 floats = 18432 B
#pragma unroll
    for (int j = 0; j < 4; ++j) {
        stg[tid * 9 + 2 * j]     = (float)pool2[j][0];
        stg[tid * 9 + 2 * j + 1] = (float)pool2[j][1];
    }
    stg[tid * 9 + 8] = lsum;         // per-thread w-sum rides slot 8
    __syncthreads();

    // pooled[d]: lanes with quad == d>>3 carry pool[j]; their lsum sums to total
    if (tid < kD) {
        const int q = tid >> 3, j = tid & 7;
        float s = 0.0f, sw = 0.0f;
        for (int w8 = 0; w8 < 8; ++w8)
            for (int l = 0; l < 16; ++l) {
                const float* row = stg + (w8 * 64 + q * 16 + l) * 9;
                s += row[j];
                sw += row[8];
            }
        sh_pooled[tid] = s / sw;
    }
    __syncthreads();

    // ---- MLP head ----
    if (tid < kA) {
        float o = b1[tid];
#pragma unroll
        for (int d = 0; d < kD; ++d) o = fmaf(sh_pooled[d], W1[d * kA + tid], o);
        sh_o1[tid] = fmaxf(o, 0.0f);
    }
    __syncthreads();
    if (tid < 8) {
        float o = b2[tid];
#pragma unroll
        for (int a = 0; a < kA; ++a) o = fmaf(sh_o1[a], W2[a * 8 + tid], o);
        sh_o2[tid] = fmaxf(o, 0.0f);
    }
    __syncthreads();
    if (tid == 0) {
        float z = bf[0];
#pragma unroll
        for (int j = 0; j < 8; ++j) z = fmaf(sh_o2[j], Wf[j], z);
        out[b] = 1.0f / (1.0f + __expf(-z));
    }
}

extern "C" void kernel_launch(void* const* d_in, const int* in_sizes, int n_in,
                              void* d_out, int out_size, void* d_ws, size_t ws_size,
                              hipStream_t stream) {
    const int*   x   = (const int*)d_in[0];
    const float* Emb = (const float*)d_in[1];
    const float* W   = (const float*)d_in[2];
    const float* bb  = (const float*)d_in[3];
    const float* h   = (const float*)d_in[4];
    const float* W1  = (const float*)d_in[5];
    const float* b1  = (const float*)d_in[6];
    const float* W2  = (const float*)d_in[7];
    const float* b2  = (const float*)d_in[8];
    const float* Wf  = (const float*)d_in[9];
    const float* bf  = (const float*)d_in[10];
    float* out = (float*)d_out;

    afm_kernel<<<1024, kNT, 0, stream>>>(x, Emb, W, bb, h, W1, b1, W2, b2, Wf, bf, out);
}

// Round 17
// 104.612 us; speedup vs baseline: 1.8240x; 1.0237x over previous
//
#include <hip/hip_runtime.h>
#include <math.h>

// AFM fused single-pass, row-run schedule, butterfly-free (R12, session best):
// one block = one sample, 512 threads (8 waves). Wave owns row r; er loaded
// once/row. Per 16-col tile:
//   MFMA1: S^T(16a x 16p) = W^T @ HB^T  (mfma_f32_16x16x32_f16, C = bias)
//   relu+pack -> B-frag;  MFMA2: L = H_bcast @ relu(S^T)  (mfma_f32_16x16x16f16)
//   -> EVERY lane holds logit_p for its col p in acc2[0]; no shuffles at all.
// w = exp2(logit*log2e) (no-max softmax: |logit| < ~0.5), pool in packed f16.
// lsum rides the staging buffer's 9th slot.
// NOTE (R13-R16): loop-carried vector state / er-folded accu structures end in
// alloca -> 0.25-0.5 GB scratch HBM churn; switch-unrolled hoists are neutral.
// This per-tile-local form is the proven optimum of the explored family.
constexpr int kT = 100;
constexpr int kD = 32;
constexpr int kA = 16;
constexpr int kESH = 40;     // e row stride in halfs (80 B)
constexpr int kRows = 116;   // 100 real + 16 zero-pad rows (tail reads <= row 114)
constexpr int kNT = 512;     // 8 waves

typedef float    float4v __attribute__((ext_vector_type(4)));
typedef __fp16   fp16x2  __attribute__((ext_vector_type(2)));
typedef __fp16   half4   __attribute__((ext_vector_type(4)));
typedef __fp16   half8   __attribute__((ext_vector_type(8)));
typedef _Float16 half4v  __attribute__((ext_vector_type(4)));
typedef _Float16 half8v  __attribute__((ext_vector_type(8)));

#if __has_builtin(__builtin_amdgcn_exp2f)
#define EXP2F(x) __builtin_amdgcn_exp2f(x)
#else
#define EXP2F(x) exp2f(x)
#endif

// LDS: she = 116 rows * 80 B = 9280 B; stg (512*9 floats = 18432 B) aliases after.
__global__ __launch_bounds__(kNT, 8)
void afm_kernel(const int* __restrict__ x,
                const float* __restrict__ Emb,
                const float* __restrict__ W,    // (32,16)
                const float* __restrict__ bb,   // (16,)
                const float* __restrict__ h,    // (16,)
                const float* __restrict__ W1,   // (32,16)
                const float* __restrict__ b1,   // (16,)
                const float* __restrict__ W2,   // (16,8)
                const float* __restrict__ b2,   // (8,)
                const float* __restrict__ Wf,   // (8,)
                const float* __restrict__ bf,   // (1,)
                float* __restrict__ out)        // (1024,)
{
    __shared__ __align__(16) unsigned char smem[18432];
    __shared__ float sh_pooled[kD];
    __shared__ float sh_o1[kA];
    __shared__ float sh_o2[8];

    __fp16* she = (__fp16*)smem;
    const char* sheb = (const char*)smem;

    const int tid  = threadIdx.x;
    const int b    = blockIdx.x;
    const int lane = tid & 63;
    const int wv   = tid >> 6;           // 0..7
    const int quad = lane >> 4;
    const int l15  = lane & 15;
    const int k0   = quad * 8;           // MFMA1 K slice (dims k0..k0+7)

    // ---- gather embeddings -> f16 LDS; zero the pad rows ----
    const int* xb = x + b * kT;
    for (int i = tid; i < kT * 8; i += kNT) {
        const int row = i >> 3, c4 = i & 7;
        const int v = xb[row];
        const float4 val = ((const float4*)Emb)[v * 8 + c4];
        union { fp16x2 h2[2]; half4 h4; } tmp;
        tmp.h2[0] = __builtin_amdgcn_cvt_pkrtz(val.x, val.y);
        tmp.h2[1] = __builtin_amdgcn_cvt_pkrtz(val.z, val.w);
        *(half4*)(she + row * kESH + c4 * 4) = tmp.h4;
    }
    if (tid < (kRows - kT) * kESH / 2)   // 320 u32 of zero pad (rows 100..115)
        ((unsigned int*)she)[kT * kESH / 2 + tid] = 0u;

    // ---- A-frag MFMA1: W^T f16 (lane holds W[k0+j][a=l15]); bias as C ----
    union { fp16x2 h2[4]; half8v h8; } wa;
#pragma unroll
    for (int j = 0; j < 4; ++j)
        wa.h2[j] = __builtin_amdgcn_cvt_pkrtz(W[(k0 + 2 * j) * kA + l15],
                                              W[(k0 + 2 * j + 1) * kA + l15]);
    float4v bfrag;
#pragma unroll
    for (int rg = 0; rg < 4; ++rg) bfrag[rg] = bb[quad * 4 + rg];

    // ---- A-frag MFMA2: H broadcast. lane holds A[m=l15][k=quad*4+i] = h[k]*log2e.
    union { fp16x2 h2[2]; half4v v; } hf;
    hf.h2[0] = __builtin_amdgcn_cvt_pkrtz(h[quad * 4 + 0] * 1.44269504f,
                                          h[quad * 4 + 1] * 1.44269504f);
    hf.h2[1] = __builtin_amdgcn_cvt_pkrtz(h[quad * 4 + 2] * 1.44269504f,
                                          h[quad * 4 + 3] * 1.44269504f);
    const float4v zero4 = {0.0f, 0.0f, 0.0f, 0.0f};

    const int lane_base = l15 * 80 + quad * 16;   // byte offset for ec
    __syncthreads();

    // ---- fused main loop over rows ----
    fp16x2 pool2[4];
    const fp16x2 zz = {(__fp16)0.0f, (__fp16)0.0f};
#pragma unroll
    for (int j = 0; j < 4; ++j) pool2[j] = zz;
    float lsum = 0.0f;

    union HB { half8 fp; fp16x2 h2[4]; half8v mf; };

    auto do_tile = [&](const half8& er, int coff, int rem, bool mask) {
        HB hb;
        hb.fp = er * (*(const half8*)(sheb + coff));   // 4x v_pk_mul_f16
        float4v s1 = __builtin_amdgcn_mfma_f32_16x16x32_f16(wa.h8, hb.mf, bfrag, 0, 0, 0);
        // relu + pack as B-frag of MFMA2: B[k=quad*4+rg][n=l15]
        union { fp16x2 h2[2]; half4v v; } rl;
        rl.h2[0] = __builtin_amdgcn_cvt_pkrtz(fmaxf(s1[0], 0.0f), fmaxf(s1[1], 0.0f));
        rl.h2[1] = __builtin_amdgcn_cvt_pkrtz(fmaxf(s1[2], 0.0f), fmaxf(s1[3], 0.0f));
        // L = H_bcast @ relu(S^T): every lane's acc2[0] = logit_p * log2e
        float4v l4 = __builtin_amdgcn_mfma_f32_16x16x16f16(hf.v, rl.v, zero4, 0, 0, 0);
        float w = EXP2F(l4[0]);
        if (mask) w = (l15 < rem) ? w : 0.0f;
        lsum += w;
        const fp16x2 ww = __builtin_amdgcn_cvt_pkrtz(w, w);
#pragma unroll
        for (int j = 0; j < 4; ++j)
            pool2[j] += ww * hb.h2[j];                 // v_pk_fma_f16
    };

    auto do_row = [&](int r) {
        const int len = 99 - r;                        // pairs in this row (>=1)
        const int nfull = (len - 1) >> 4;              // full 16-col tiles
        const half8 er = *(const half8*)(sheb + r * 80 + quad * 16);  // broadcast
        int coff = (r + 1) * 80 + lane_base;
        for (int j = 0; j < nfull; ++j, coff += 1280)
            do_tile(er, coff, 16, false);
        do_tile(er, coff, len - (nfull << 4), true);   // tail tile (rem in 1..16)
    };

    // rows paired (g*16+wvg, g*16+15-wvg); rotate wvg per g to balance
    for (int g = 0; g < 6; ++g) {
        const int wvg = (wv + g) & 7;
        do_row(g * 16 + wvg);
        do_row(g * 16 + 15 - wvg);
    }
    if (wv < 3) do_row(96 + wv);                       // rows 96..98

    __syncthreads();                 // she reads done; smem reusable
    float* stg = (float*)smem;       // 512 * 9 floats = 18432 B
#pragma unroll
    for (int j = 0; j < 4; ++j) {
        stg[tid * 9 + 2 * j]     = (float)pool2[j][0];
        stg[tid * 9 + 2 * j + 1] = (float)pool2[j][1];
    }
    stg[tid * 9 + 8] = lsum;         // per-thread w-sum rides slot 8
    __syncthreads();

    // pooled[d]: lanes with quad == d>>3 carry pool[j]; their lsum sums to total
    if (tid < kD) {
        const int q = tid >> 3, j = tid & 7;
        float s = 0.0f, sw = 0.0f;
        for (int w8 = 0; w8 < 8; ++w8)
            for (int l = 0; l < 16; ++l) {
                const float* row = stg + (w8 * 64 + q * 16 + l) * 9;
                s += row[j];
                sw += row[8];
            }
        sh_pooled[tid] = s / sw;
    }
    __syncthreads();

    // ---- MLP head ----
    if (tid < kA) {
        float o = b1[tid];
#pragma unroll
        for (int d = 0; d < kD; ++d) o = fmaf(sh_pooled[d], W1[d * kA + tid], o);
        sh_o1[tid] = fmaxf(o, 0.0f);
    }
    __syncthreads();
    if (tid < 8) {
        float o = b2[tid];
#pragma unroll
        for (int a = 0; a < kA; ++a) o = fmaf(sh_o1[a], W2[a * 8 + tid], o);
        sh_o2[tid] = fmaxf(o, 0.0f);
    }
    __syncthreads();
    if (tid == 0) {
        float z = bf[0];
#pragma unroll
        for (int j = 0; j < 8; ++j) z = fmaf(sh_o2[j], Wf[j], z);
        out[b] = 1.0f / (1.0f + __expf(-z));
    }
}

extern "C" void kernel_launch(void* const* d_in, const int* in_sizes, int n_in,
                              void* d_out, int out_size, void* d_ws, size_t ws_size,
                              hipStream_t stream) {
    const int*   x   = (const int*)d_in[0];
    const float* Emb = (const float*)d_in[1];
    const float* W   = (const float*)d_in[2];
    const float* bb  = (const float*)d_in[3];
    const float* h   = (const float*)d_in[4];
    const float* W1  = (const float*)d_in[5];
    const float* b1  = (const float*)d_in[6];
    const float* W2  = (const float*)d_in[7];
    const float* b2  = (const float*)d_in[8];
    const float* Wf  = (const float*)d_in[9];
    const float* bf  = (const float*)d_in[10];
    float* out = (float*)d_out;

    afm_kernel<<<1024, kNT, 0, stream>>>(x, Emb, W, bb, h, W1, b1, W2, b2, Wf, bf, out);
}